// Round 1
// baseline (281.392 us; speedup 1.0000x reference)
//
#include <hip/hip_runtime.h>
#include <hip/hip_bf16.h>
#include <math.h>

typedef __attribute__((ext_vector_type(4))) float f32x4;
typedef __attribute__((ext_vector_type(8))) short short8;

#define N_NODES 8192
#define KSEGS 4

// f32 -> bf16 bits, round-to-nearest-even (3 VALU, no header/API risk)
__device__ __forceinline__ short f2bf(float x) {
    unsigned u = __float_as_uint(x);
    u += 0x7FFFu + ((u >> 16) & 1u);
    return (short)(u >> 16);
}

__device__ __forceinline__ float sigmoid_f(float t) {
    float ex = __builtin_amdgcn_exp2f(-1.44269504088896f * t);
    return __builtin_amdgcn_rcpf(1.0f + ex);
}

// ---------------------------------------------------------------------------
// P1: h = x @ W1  [8192,500]@[500,64], plus s_src1/s_dst1 = h . a1 halves.
// One wave per 2 rows; W1 loads coalesced across lanes, x loads wave-uniform.
// ---------------------------------------------------------------------------
__global__ __launch_bounds__(256) void p1_kernel(
    const float* __restrict__ x, const float* __restrict__ W1,
    const float* __restrict__ a1, float* __restrict__ h,
    float* __restrict__ ssrc, float* __restrict__ sdst)
{
    int gw   = (blockIdx.x * blockDim.x + threadIdx.x) >> 6;  // global wave id
    int lane = threadIdx.x & 63;
    int r0   = gw * 2;
    if (r0 >= N_NODES) return;
    const float* x0 = x + (size_t)r0 * 500;
    const float* x1 = x0 + 500;
    float acc0 = 0.f, acc1 = 0.f;
    for (int k = 0; k < 500; k += 4) {
        float w0 = W1[(k + 0) * 64 + lane];
        float w1 = W1[(k + 1) * 64 + lane];
        float w2 = W1[(k + 2) * 64 + lane];
        float w3 = W1[(k + 3) * 64 + lane];
        acc0 = fmaf(x0[k], w0, acc0); acc0 = fmaf(x0[k + 1], w1, acc0);
        acc0 = fmaf(x0[k + 2], w2, acc0); acc0 = fmaf(x0[k + 3], w3, acc0);
        acc1 = fmaf(x1[k], w0, acc1); acc1 = fmaf(x1[k + 1], w1, acc1);
        acc1 = fmaf(x1[k + 2], w2, acc1); acc1 = fmaf(x1[k + 3], w3, acc1);
    }
    h[(size_t)r0 * 64 + lane]       = acc0;
    h[(size_t)(r0 + 1) * 64 + lane] = acc1;
    float a_s = a1[lane], a_d = a1[64 + lane];
    float p0s = acc0 * a_s, p0d = acc0 * a_d;
    float p1s = acc1 * a_s, p1d = acc1 * a_d;
    for (int off = 32; off > 0; off >>= 1) {
        p0s += __shfl_down(p0s, off); p0d += __shfl_down(p0d, off);
        p1s += __shfl_down(p1s, off); p1d += __shfl_down(p1d, off);
    }
    if (lane == 0) {
        ssrc[r0] = p0s; sdst[r0] = p0d;
        ssrc[r0 + 1] = p1s; sdst[r0 + 1] = p1d;
    }
}

// ---------------------------------------------------------------------------
// Swizzle f32 matrix [nrows x ncols] into bf16 B-fragment order:
// hB[kb][nb][lane][i] = bf16( h[kb*32 + (lane>>4)*8 + i][nb*16 + (lane&15)] )
// so the fused kernel loads one dwordx4 per lane per n-block.
// ---------------------------------------------------------------------------
__global__ __launch_bounds__(256) void swizzle_kernel(
    const float* __restrict__ h, short* __restrict__ hB,
    int nblk, int ncols, int total)
{
    int tid = blockIdx.x * 256 + threadIdx.x;
    if (tid >= total) return;
    int i  = tid & 7;
    int l  = (tid >> 3) & 63;
    int t2 = tid >> 9;
    int nb = t2 % nblk;
    int kb = t2 / nblk;
    int row = kb * 32 + (l >> 4) * 8 + i;
    int col = nb * 16 + (l & 15);
    hB[tid] = f2bf(h[(size_t)row * ncols + col]);
}

// ---------------------------------------------------------------------------
// Fused GAT layer pass: out_partial = (sigmoid(s_src_i + s_dst_j) * adj) @ h
// with per-row sum of att^2 accumulated in the same adj pass.
// Block = 4 waves x 16 rows = 64 rows; grid.y = K segment.
// A-fragments built on the fly from adj (f32) in registers; B from hB (bf16).
// ---------------------------------------------------------------------------
template <int NBLK>
__global__ __launch_bounds__(256) void gat_fused(
    const float* __restrict__ adj, const float* __restrict__ ssrc,
    const float* __restrict__ sdst, const short* __restrict__ hB,
    float* __restrict__ outp, float* __restrict__ normp, int kseg_len)
{
    const int lane = threadIdx.x & 63;
    const int w    = threadIdx.x >> 6;
    const int rb   = blockIdx.x;
    const int seg  = blockIdx.y;
    const int r    = lane & 15;
    const int g    = lane >> 4;
    const int my_row = rb * 64 + w * 16 + r;
    const float s_i  = ssrc[my_row];
    const float* arow = adj + (size_t)my_row * N_NODES;

    f32x4 acc[NBLK];
#pragma unroll
    for (int nb = 0; nb < NBLK; ++nb) acc[nb] = (f32x4){0.f, 0.f, 0.f, 0.f};
    float nacc = 0.f;

    const int k0 = seg * kseg_len;
    const int k1 = k0 + kseg_len;
    for (int k = k0; k < k1; k += 32) {
        const int kb8 = k + g * 8;
        f32x4 a0  = *(const f32x4*)(arow + kb8);
        f32x4 a1v = *(const f32x4*)(arow + kb8 + 4);
        f32x4 d0  = *(const f32x4*)(sdst + kb8);
        f32x4 d1  = *(const f32x4*)(sdst + kb8 + 4);
        short8 af;
#pragma unroll
        for (int i = 0; i < 4; ++i) {
            float e   = sigmoid_f(s_i + d0[i]);
            float att = e * a0[i];
            nacc = fmaf(att, att, nacc);
            af[i] = f2bf(att);
        }
#pragma unroll
        for (int i = 0; i < 4; ++i) {
            float e   = sigmoid_f(s_i + d1[i]);
            float att = e * a1v[i];
            nacc = fmaf(att, att, nacc);
            af[4 + i] = f2bf(att);
        }
        const int kb = k >> 5;
#pragma unroll
        for (int nb = 0; nb < NBLK; ++nb) {
            short8 bf = *(const short8*)(hB + ((size_t)(kb * NBLK + nb) * 64 + lane) * 8);
            acc[nb] = __builtin_amdgcn_mfma_f32_16x16x32_bf16(af, bf, acc[nb], 0, 0, 0);
        }
    }

    // per-row norm: lanes {r, r+16, r+32, r+48} hold partials for row r
    nacc += __shfl_xor(nacc, 16);
    nacc += __shfl_xor(nacc, 32);
    if (lane < 16) normp[(size_t)seg * N_NODES + my_row] = nacc;

    const int F = NBLK * 16;
#pragma unroll
    for (int nb = 0; nb < NBLK; ++nb) {
#pragma unroll
        for (int rr = 0; rr < 4; ++rr) {
            int grow = rb * 64 + w * 16 + g * 4 + rr;   // C/D: row=(lane>>4)*4+reg
            outp[((size_t)seg * N_NODES + grow) * F + nb * 16 + (lane & 15)] = acc[nb][rr];
        }
    }
}

// ---------------------------------------------------------------------------
// R1: h1[i][f] = sum_seg outp1 / (sqrt(sum_seg normp1) + 1e-10)
// ---------------------------------------------------------------------------
__global__ __launch_bounds__(256) void r1_kernel(
    const float* __restrict__ outp, const float* __restrict__ normp,
    float* __restrict__ h1)
{
    int tid = blockIdx.x * 256 + threadIdx.x;   // 8192*64
    int i = tid >> 6, f = tid & 63;
    float s = 0.f, n = 0.f;
#pragma unroll
    for (int sg = 0; sg < KSEGS; ++sg) {
        s += outp[((size_t)sg * N_NODES + i) * 64 + f];
        n += normp[sg * N_NODES + i];
    }
    h1[tid] = s / (sqrtf(n) + 1e-10f);
}

// ---------------------------------------------------------------------------
// P2: z = h1 @ W2 (padded to 16 cols with zeros), s_src2/s_dst2 = z . a2 halves
// ---------------------------------------------------------------------------
__global__ __launch_bounds__(256) void p2_kernel(
    const float* __restrict__ h1, const float* __restrict__ W2,
    const float* __restrict__ a2, float* __restrict__ z,
    float* __restrict__ ssrc2, float* __restrict__ sdst2)
{
    int i = blockIdx.x * 256 + threadIdx.x;
    if (i >= N_NODES) return;
    float zz[10];
#pragma unroll
    for (int c = 0; c < 10; ++c) zz[c] = 0.f;
    for (int f = 0; f < 64; ++f) {
        float hv = h1[(size_t)i * 64 + f];
#pragma unroll
        for (int c = 0; c < 10; ++c) zz[c] = fmaf(hv, W2[f * 10 + c], zz[c]);
    }
    float s1 = 0.f, s2 = 0.f;
#pragma unroll
    for (int c = 0; c < 10; ++c) {
        s1 = fmaf(zz[c], a2[c], s1);
        s2 = fmaf(zz[c], a2[10 + c], s2);
        z[(size_t)i * 16 + c] = zz[c];
    }
#pragma unroll
    for (int c = 10; c < 16; ++c) z[(size_t)i * 16 + c] = 0.f;
    ssrc2[i] = s1; sdst2[i] = s2;
}

// ---------------------------------------------------------------------------
// R2: h2 = partials/norm, then log_softmax over 10 classes -> d_out
// ---------------------------------------------------------------------------
__global__ __launch_bounds__(256) void r2_kernel(
    const float* __restrict__ outp, const float* __restrict__ normp,
    float* __restrict__ out)
{
    int i = blockIdx.x * 256 + threadIdx.x;
    if (i >= N_NODES) return;
    float n = 0.f;
#pragma unroll
    for (int sg = 0; sg < KSEGS; ++sg) n += normp[sg * N_NODES + i];
    float inv = 1.0f / (sqrtf(n) + 1e-10f);
    float v[10];
    float m = -1e30f;
#pragma unroll
    for (int c = 0; c < 10; ++c) {
        float s = 0.f;
#pragma unroll
        for (int sg = 0; sg < KSEGS; ++sg)
            s += outp[((size_t)sg * N_NODES + i) * 16 + c];
        v[c] = s * inv;
        m = fmaxf(m, v[c]);
    }
    float es = 0.f;
#pragma unroll
    for (int c = 0; c < 10; ++c) es += expf(v[c] - m);
    float lse = m + logf(es);
#pragma unroll
    for (int c = 0; c < 10; ++c) out[(size_t)i * 10 + c] = v[c] - lse;
}

extern "C" void kernel_launch(void* const* d_in, const int* in_sizes, int n_in,
                              void* d_out, int out_size, void* d_ws, size_t ws_size,
                              hipStream_t stream)
{
    const float* x   = (const float*)d_in[0];
    const float* adj = (const float*)d_in[1];
    const float* W1  = (const float*)d_in[2];
    const float* a1  = (const float*)d_in[3];
    const float* W2  = (const float*)d_in[4];
    const float* a2  = (const float*)d_in[5];
    float* out = (float*)d_out;

    char* ws = (char*)d_ws;
    size_t off = 0;
    auto alloc = [&](size_t bytes) -> void* {
        void* p = ws + off;
        off += (bytes + 255) & ~(size_t)255;
        return p;
    };
    float* h      = (float*)alloc((size_t)N_NODES * 64 * 4);
    float* ssrc1  = (float*)alloc((size_t)N_NODES * 4);
    float* sdst1  = (float*)alloc((size_t)N_NODES * 4);
    short* hB1    = (short*)alloc((size_t)N_NODES * 64 * 2);
    float* outp1  = (float*)alloc((size_t)KSEGS * N_NODES * 64 * 4);
    float* normp1 = (float*)alloc((size_t)KSEGS * N_NODES * 4);
    float* h1     = (float*)alloc((size_t)N_NODES * 64 * 4);
    float* z      = (float*)alloc((size_t)N_NODES * 16 * 4);
    float* ssrc2  = (float*)alloc((size_t)N_NODES * 4);
    float* sdst2  = (float*)alloc((size_t)N_NODES * 4);
    short* zB     = (short*)alloc((size_t)N_NODES * 16 * 2);
    float* outp2  = (float*)alloc((size_t)KSEGS * N_NODES * 16 * 4);
    float* normp2 = (float*)alloc((size_t)KSEGS * N_NODES * 4);

    const int kseg_len = N_NODES / KSEGS;

    hipLaunchKernelGGL(p1_kernel, dim3(1024), dim3(256), 0, stream,
                       x, W1, a1, h, ssrc1, sdst1);
    hipLaunchKernelGGL(swizzle_kernel, dim3(2048), dim3(256), 0, stream,
                       h, hB1, 4, 64, N_NODES * 64);
    hipLaunchKernelGGL((gat_fused<4>), dim3(128, KSEGS), dim3(256), 0, stream,
                       adj, ssrc1, sdst1, hB1, outp1, normp1, kseg_len);
    hipLaunchKernelGGL(r1_kernel, dim3(2048), dim3(256), 0, stream,
                       outp1, normp1, h1);
    hipLaunchKernelGGL(p2_kernel, dim3(32), dim3(256), 0, stream,
                       h1, W2, a2, z, ssrc2, sdst2);
    hipLaunchKernelGGL(swizzle_kernel, dim3(512), dim3(256), 0, stream,
                       z, zB, 1, 16, N_NODES * 16);
    hipLaunchKernelGGL((gat_fused<1>), dim3(128, KSEGS), dim3(256), 0, stream,
                       adj, ssrc2, sdst2, zB, outp2, normp2, kseg_len);
    hipLaunchKernelGGL(r2_kernel, dim3(32), dim3(256), 0, stream,
                       outp2, normp2, out);
}

// Round 2
// 215.218 us; speedup vs baseline: 1.3075x; 1.3075x over previous
//
#include <hip/hip_runtime.h>
#include <hip/hip_bf16.h>
#include <math.h>

typedef __attribute__((ext_vector_type(4))) float f32x4;
typedef __attribute__((ext_vector_type(8))) short short8;

#define N_NODES 8192
#define KSEGS 8
#define WAVES 4
#define SEGLEN (N_NODES / KSEGS)   // 1024
#define WKSEG  (SEGLEN / WAVES)    // 256 columns per wave
#define P1_ROWS 8

// f32 -> bf16 bits, round-to-nearest-even
__device__ __forceinline__ short f2bf(float x) {
    unsigned u = __float_as_uint(x);
    u += 0x7FFFu + ((u >> 16) & 1u);
    return (short)(u >> 16);
}

__device__ __forceinline__ float sigmoid_f(float t) {
    float ex = __builtin_amdgcn_exp2f(-1.44269504088896f * t);
    return __builtin_amdgcn_rcpf(1.0f + ex);
}

// ---------------------------------------------------------------------------
// P1: h = x @ W1  [8192,500]@[500,64], plus s_src1/s_dst1 = h . a1 halves.
// 8 rows per wave: W1 re-reads from L2 amortized 4x vs before.
// ---------------------------------------------------------------------------
__global__ __launch_bounds__(256) void p1_kernel(
    const float* __restrict__ x, const float* __restrict__ W1,
    const float* __restrict__ a1, float* __restrict__ h,
    float* __restrict__ ssrc, float* __restrict__ sdst)
{
    int gw   = (blockIdx.x * blockDim.x + threadIdx.x) >> 6;
    int lane = threadIdx.x & 63;
    int r0   = gw * P1_ROWS;
    if (r0 >= N_NODES) return;
    float acc[P1_ROWS];
#pragma unroll
    for (int r = 0; r < P1_ROWS; ++r) acc[r] = 0.f;
    for (int k = 0; k < 500; k += 2) {
        float w0 = W1[(k + 0) * 64 + lane];
        float w1 = W1[(k + 1) * 64 + lane];
#pragma unroll
        for (int r = 0; r < P1_ROWS; ++r) {
            const float* xr = x + (size_t)(r0 + r) * 500;
            acc[r] = fmaf(xr[k], w0, acc[r]);
            acc[r] = fmaf(xr[k + 1], w1, acc[r]);
        }
    }
    float a_s = a1[lane], a_d = a1[64 + lane];
#pragma unroll
    for (int r = 0; r < P1_ROWS; ++r) {
        h[(size_t)(r0 + r) * 64 + lane] = acc[r];
        float ps = acc[r] * a_s, pd = acc[r] * a_d;
        for (int off = 32; off > 0; off >>= 1) {
            ps += __shfl_down(ps, off); pd += __shfl_down(pd, off);
        }
        if (lane == 0) { ssrc[r0 + r] = ps; sdst[r0 + r] = pd; }
    }
}

// ---------------------------------------------------------------------------
// Swizzle f32 matrix into bf16 B-fragment order:
// hB[kb][nb][lane][i] = bf16( h[kb*32 + (lane>>4)*8 + i][nb*16 + (lane&15)] )
// ---------------------------------------------------------------------------
__global__ __launch_bounds__(256) void swizzle_kernel(
    const float* __restrict__ h, short* __restrict__ hB,
    int nblk, int ncols, int total)
{
    int tid = blockIdx.x * 256 + threadIdx.x;
    if (tid >= total) return;
    int i  = tid & 7;
    int l  = (tid >> 3) & 63;
    int t2 = tid >> 9;
    int nb = t2 % nblk;
    int kb = t2 / nblk;
    int row = kb * 32 + (l >> 4) * 8 + i;
    int col = nb * 16 + (l & 15);
    hB[tid] = f2bf(h[(size_t)row * ncols + col]);
}

// ---------------------------------------------------------------------------
// Fused GAT layer pass. Block = 4 waves, ALL on the same 16 rows, each wave
// takes a 256-col quarter of the block's 1024-col K segment. Per-block LDS
// reduction combines the 4 waves; grid = (512 row-blocks, 8 K-segments)
// = 4096 blocks -> 32 waves/CU.
// ---------------------------------------------------------------------------
template <int NBLK>
__global__ __launch_bounds__(256) void gat_fused(
    const float* __restrict__ adj, const float* __restrict__ ssrc,
    const float* __restrict__ sdst, const short* __restrict__ hB,
    float* __restrict__ outp, float* __restrict__ normp)
{
    __shared__ float red[WAVES][NBLK * 4][72];   // padded: conflict-free
    __shared__ float rednorm[WAVES][16];
    const int lane = threadIdx.x & 63;
    const int w    = threadIdx.x >> 6;
    const int rb   = blockIdx.x;
    const int seg  = blockIdx.y;
    const int r    = lane & 15;
    const int g    = lane >> 4;
    const int my_row = rb * 16 + r;
    const float s_i  = ssrc[my_row];
    const float* arow = adj + (size_t)my_row * N_NODES;

    f32x4 acc[NBLK];
#pragma unroll
    for (int nb = 0; nb < NBLK; ++nb) acc[nb] = (f32x4){0.f, 0.f, 0.f, 0.f};
    float nacc = 0.f;

    const int k0 = seg * SEGLEN + w * WKSEG;
#pragma unroll 2
    for (int kk = 0; kk < WKSEG; kk += 32) {
        const int k   = k0 + kk;
        const int kb8 = k + g * 8;
        f32x4 a0  = *(const f32x4*)(arow + kb8);
        f32x4 a1v = *(const f32x4*)(arow + kb8 + 4);
        f32x4 d0  = *(const f32x4*)(sdst + kb8);
        f32x4 d1  = *(const f32x4*)(sdst + kb8 + 4);
        short8 af;
#pragma unroll
        for (int i = 0; i < 4; ++i) {
            float e   = sigmoid_f(s_i + d0[i]);
            float att = e * a0[i];
            nacc = fmaf(att, att, nacc);
            af[i] = f2bf(att);
        }
#pragma unroll
        for (int i = 0; i < 4; ++i) {
            float e   = sigmoid_f(s_i + d1[i]);
            float att = e * a1v[i];
            nacc = fmaf(att, att, nacc);
            af[4 + i] = f2bf(att);
        }
        const int kb = k >> 5;
#pragma unroll
        for (int nb = 0; nb < NBLK; ++nb) {
            short8 bf = *(const short8*)(hB + ((size_t)(kb * NBLK + nb) * 64 + lane) * 8);
            acc[nb] = __builtin_amdgcn_mfma_f32_16x16x32_bf16(af, bf, acc[nb], 0, 0, 0);
        }
    }

    // wave-internal norm partial: lanes {r, r+16, r+32, r+48} -> lane r
    nacc += __shfl_xor(nacc, 16);
    nacc += __shfl_xor(nacc, 32);

    // dump wave accumulators to LDS (store: consecutive lanes -> consecutive addrs)
#pragma unroll
    for (int nb = 0; nb < NBLK; ++nb)
#pragma unroll
        for (int rr = 0; rr < 4; ++rr)
            red[w][nb * 4 + rr][lane] = acc[nb][rr];
    if (lane < 16) rednorm[w][lane] = nacc;
    __syncthreads();

    // cross-wave reduce + coalesced global write of this block's partial
    constexpr int F = NBLK * 16;
#pragma unroll
    for (int j = 0; j < NBLK; ++j) {
        int o   = threadIdx.x + 256 * j;       // 0 .. 16*F-1
        int row = o / F;
        int f   = o % F;
        int gg = row >> 2, rr = row & 3, c = f & 15, nb = f >> 4;
        float s = red[0][nb * 4 + rr][gg * 16 + c]
                + red[1][nb * 4 + rr][gg * 16 + c]
                + red[2][nb * 4 + rr][gg * 16 + c]
                + red[3][nb * 4 + rr][gg * 16 + c];
        outp[((size_t)seg * N_NODES + rb * 16 + row) * F + f] = s;
    }
    if (threadIdx.x < 16) {
        float n = rednorm[0][threadIdx.x] + rednorm[1][threadIdx.x]
                + rednorm[2][threadIdx.x] + rednorm[3][threadIdx.x];
        normp[(size_t)seg * N_NODES + rb * 16 + threadIdx.x] = n;
    }
}

// ---------------------------------------------------------------------------
// R1: h1[i][f] = sum_seg outp1 / (sqrt(sum_seg normp1) + 1e-10)
// ---------------------------------------------------------------------------
__global__ __launch_bounds__(256) void r1_kernel(
    const float* __restrict__ outp, const float* __restrict__ normp,
    float* __restrict__ h1)
{
    int tid = blockIdx.x * 256 + threadIdx.x;   // 8192*64
    int i = tid >> 6, f = tid & 63;
    float s = 0.f, n = 0.f;
#pragma unroll
    for (int sg = 0; sg < KSEGS; ++sg) {
        s += outp[((size_t)sg * N_NODES + i) * 64 + f];
        n += normp[sg * N_NODES + i];
    }
    h1[tid] = s / (sqrtf(n) + 1e-10f);
}

// ---------------------------------------------------------------------------
// P2: z = h1 @ W2 (padded to 16 cols), s_src2/s_dst2 = z . a2 halves
// ---------------------------------------------------------------------------
__global__ __launch_bounds__(256) void p2_kernel(
    const float* __restrict__ h1, const float* __restrict__ W2,
    const float* __restrict__ a2, float* __restrict__ z,
    float* __restrict__ ssrc2, float* __restrict__ sdst2)
{
    int i = blockIdx.x * 256 + threadIdx.x;
    if (i >= N_NODES) return;
    float zz[10];
#pragma unroll
    for (int c = 0; c < 10; ++c) zz[c] = 0.f;
    for (int f = 0; f < 64; ++f) {
        float hv = h1[(size_t)i * 64 + f];
#pragma unroll
        for (int c = 0; c < 10; ++c) zz[c] = fmaf(hv, W2[f * 10 + c], zz[c]);
    }
    float s1 = 0.f, s2 = 0.f;
#pragma unroll
    for (int c = 0; c < 10; ++c) {
        s1 = fmaf(zz[c], a2[c], s1);
        s2 = fmaf(zz[c], a2[10 + c], s2);
        z[(size_t)i * 16 + c] = zz[c];
    }
#pragma unroll
    for (int c = 10; c < 16; ++c) z[(size_t)i * 16 + c] = 0.f;
    ssrc2[i] = s1; sdst2[i] = s2;
}

// ---------------------------------------------------------------------------
// R2: h2 = partials/norm, then log_softmax over 10 classes -> d_out
// ---------------------------------------------------------------------------
__global__ __launch_bounds__(256) void r2_kernel(
    const float* __restrict__ outp, const float* __restrict__ normp,
    float* __restrict__ out)
{
    int i = blockIdx.x * 256 + threadIdx.x;
    if (i >= N_NODES) return;
    float n = 0.f;
#pragma unroll
    for (int sg = 0; sg < KSEGS; ++sg) n += normp[sg * N_NODES + i];
    float inv = 1.0f / (sqrtf(n) + 1e-10f);
    float v[10];
    float m = -1e30f;
#pragma unroll
    for (int c = 0; c < 10; ++c) {
        float s = 0.f;
#pragma unroll
        for (int sg = 0; sg < KSEGS; ++sg)
            s += outp[((size_t)sg * N_NODES + i) * 16 + c];
        v[c] = s * inv;
        m = fmaxf(m, v[c]);
    }
    float es = 0.f;
#pragma unroll
    for (int c = 0; c < 10; ++c) es += expf(v[c] - m);
    float lse = m + logf(es);
#pragma unroll
    for (int c = 0; c < 10; ++c) out[(size_t)i * 10 + c] = v[c] - lse;
}

extern "C" void kernel_launch(void* const* d_in, const int* in_sizes, int n_in,
                              void* d_out, int out_size, void* d_ws, size_t ws_size,
                              hipStream_t stream)
{
    const float* x   = (const float*)d_in[0];
    const float* adj = (const float*)d_in[1];
    const float* W1  = (const float*)d_in[2];
    const float* a1  = (const float*)d_in[3];
    const float* W2  = (const float*)d_in[4];
    const float* a2  = (const float*)d_in[5];
    float* out = (float*)d_out;

    char* ws = (char*)d_ws;
    size_t off = 0;
    auto alloc = [&](size_t bytes) -> void* {
        void* p = ws + off;
        off += (bytes + 255) & ~(size_t)255;
        return p;
    };
    float* h      = (float*)alloc((size_t)N_NODES * 64 * 4);
    float* ssrc1  = (float*)alloc((size_t)N_NODES * 4);
    float* sdst1  = (float*)alloc((size_t)N_NODES * 4);
    short* hB1    = (short*)alloc((size_t)N_NODES * 64 * 2);
    float* outp1  = (float*)alloc((size_t)KSEGS * N_NODES * 64 * 4);
    float* normp1 = (float*)alloc((size_t)KSEGS * N_NODES * 4);
    float* h1     = (float*)alloc((size_t)N_NODES * 64 * 4);
    float* z      = (float*)alloc((size_t)N_NODES * 16 * 4);
    float* ssrc2  = (float*)alloc((size_t)N_NODES * 4);
    float* sdst2  = (float*)alloc((size_t)N_NODES * 4);
    short* zB     = (short*)alloc((size_t)N_NODES * 16 * 2);
    float* outp2  = (float*)alloc((size_t)KSEGS * N_NODES * 16 * 4);
    float* normp2 = (float*)alloc((size_t)KSEGS * N_NODES * 4);

    hipLaunchKernelGGL(p1_kernel, dim3(N_NODES / P1_ROWS / 4), dim3(256), 0, stream,
                       x, W1, a1, h, ssrc1, sdst1);
    hipLaunchKernelGGL(swizzle_kernel, dim3(2048), dim3(256), 0, stream,
                       h, hB1, 4, 64, N_NODES * 64);
    hipLaunchKernelGGL((gat_fused<4>), dim3(N_NODES / 16, KSEGS), dim3(256), 0, stream,
                       adj, ssrc1, sdst1, hB1, outp1, normp1);
    hipLaunchKernelGGL(r1_kernel, dim3(2048), dim3(256), 0, stream,
                       outp1, normp1, h1);
    hipLaunchKernelGGL(p2_kernel, dim3(32), dim3(256), 0, stream,
                       h1, W2, a2, z, ssrc2, sdst2);
    hipLaunchKernelGGL(swizzle_kernel, dim3(512), dim3(256), 0, stream,
                       z, zB, 1, 16, N_NODES * 16);
    hipLaunchKernelGGL((gat_fused<1>), dim3(N_NODES / 16, KSEGS), dim3(256), 0, stream,
                       adj, ssrc2, sdst2, zB, outp2, normp2);
    hipLaunchKernelGGL(r2_kernel, dim3(32), dim3(256), 0, stream,
                       outp2, normp2, out);
}